// Round 12
// baseline (103.394 us; speedup 1.0000x reference)
//
#include <hip/hip_runtime.h>

// CoLL fused, 2 dispatches, NO atomics:
//  A) reduce_k : per-block min/max partials -> d_ws (2048 float2)
//  B) coll_k   : partial-reduce prologue, then fused 3x3 stencil.
//     co[8][8] table lives in ONE VGPR per lane (64 entries == wave);
//     gather co[bp][bq] via ds_bpermute (conflict-free crossbar).
//     y(p,c) = sum_{3x3} w[dq] * x(q,c) * co[bin(p,c), bin(q,c)]
// N=8, H=128, W=128, C=64, NUM_BINS=8. One image = 128*128*16 = 262144 float4.

static constexpr int IMG4 = 128 * 128 * 16;
static constexpr int TOT4 = 8 * IMG4;            // 2097152 float4
static constexpr int RBLK = 2048;                // reduce blocks
static constexpr int RSTRIDE = RBLK * 256;       // 524288; TOT4/RSTRIDE = 4
static constexpr int NBLK = 1024, NTHR = 256;    // coll grid: NBLK*NTHR == IMG4

__device__ __forceinline__ int qbin(float v, float xmin, float scale) {
    float t = (v - xmin) * scale;   // >= 0 exactly (v >= xmin in f32)
    t = fminf(t, 7.0f);
    return (int)t;                  // trunc == floor for t >= 0
}

__global__ __launch_bounds__(256) void reduce_k(const float4* __restrict__ x4,
                                                float2* __restrict__ part) {
    const int i = blockIdx.x * 256 + threadIdx.x;
    float4 a = x4[i];
    float4 b = x4[i + RSTRIDE];
    float4 c = x4[i + 2 * RSTRIDE];
    float4 d = x4[i + 3 * RSTRIDE];
    float lmin = fminf(fminf(fminf(a.x, a.y), fminf(a.z, a.w)),
                       fminf(fminf(b.x, b.y), fminf(b.z, b.w)));
    float lmax = fmaxf(fmaxf(fmaxf(a.x, a.y), fmaxf(a.z, a.w)),
                       fmaxf(fmaxf(b.x, b.y), fmaxf(b.z, b.w)));
    lmin = fminf(lmin, fminf(fminf(fminf(c.x, c.y), fminf(c.z, c.w)),
                             fminf(fminf(d.x, d.y), fminf(d.z, d.w))));
    lmax = fmaxf(lmax, fmaxf(fmaxf(fmaxf(c.x, c.y), fmaxf(c.z, c.w)),
                             fmaxf(fmaxf(d.x, d.y), fmaxf(d.z, d.w))));
#pragma unroll
    for (int off = 32; off; off >>= 1) {
        lmin = fminf(lmin, __shfl_xor(lmin, off, 64));
        lmax = fmaxf(lmax, __shfl_xor(lmax, off, 64));
    }
    __shared__ float smin[4], smax[4];
    const int wid = threadIdx.x >> 6, lane = threadIdx.x & 63;
    if (lane == 0) { smin[wid] = lmin; smax[wid] = lmax; }
    __syncthreads();
    if (threadIdx.x == 0) {
        part[blockIdx.x] = make_float2(
            fminf(fminf(smin[0], smin[1]), fminf(smin[2], smin[3])),
            fmaxf(fmaxf(smax[0], smax[1]), fmaxf(smax[2], smax[3])));
    }
}

__global__ __launch_bounds__(256) void coll_k(const float4* __restrict__ x4,
                                              const float* __restrict__ co,
                                              const float* __restrict__ wsp,
                                              float4* __restrict__ y4,
                                              const float2* __restrict__ part) {
    __shared__ float sred[8];

    // prologue: every block redundantly reduces the 2048 partials (16 KB, L2-hot)
    float gmin = 3.4028235e38f, gmax = -3.4028235e38f;
#pragma unroll
    for (int j = 0; j < 8; ++j) {
        float2 p = part[threadIdx.x * 8 + j];
        gmin = fminf(gmin, p.x);
        gmax = fmaxf(gmax, p.y);
    }
#pragma unroll
    for (int off = 32; off; off >>= 1) {
        gmin = fminf(gmin, __shfl_xor(gmin, off, 64));
        gmax = fmaxf(gmax, __shfl_xor(gmax, off, 64));
    }
    const int wid = threadIdx.x >> 6, lane = threadIdx.x & 63;
    if (lane == 0) { sred[wid] = gmin; sred[4 + wid] = gmax; }
    __syncthreads();
    const float xmin = fminf(fminf(sred[0], sred[1]), fminf(sred[2], sred[3]));
    const float xmax = fmaxf(fmaxf(sred[4], sred[5]), fmaxf(sred[6], sred[7]));
    const float scale = 8.0f / ((xmax - xmin) + 1e-8f);

    // co table: one VGPR per lane holds co[lane] (64 entries == one wave)
    const int co_i = __float_as_int(co[lane]);

    const int ofs = blockIdx.x * 256 + threadIdx.x;  // within-image float4 idx
    const int w = (ofs >> 4) & 127;
    const int h = (ofs >> 11) & 127;
    const bool wm = (w > 0), wp = (w < 127), hm = (h > 0), hp = (h < 127);

    const bool v0 = hm && wm, v1 = hm, v2 = hm && wp;
    const bool v3 = wm,                v5 = wp;
    const bool v6 = hp && wm, v7 = hp, v8 = hp && wp;

    // w_spatial via uniform (scalar) loads; zeroed per-lane for invalid taps
    const float wz0 = v0 ? wsp[0] : 0.f, wz1 = v1 ? wsp[1] : 0.f;
    const float wz2 = v2 ? wsp[2] : 0.f, wz3 = v3 ? wsp[3] : 0.f;
    const float wz4 = wsp[4];
    const float wz5 = v5 ? wsp[5] : 0.f, wz6 = v6 ? wsp[6] : 0.f;
    const float wz7 = v7 ? wsp[7] : 0.f, wz8 = v8 ? wsp[8] : 0.f;

#pragma unroll 1
    for (int k = 0; k < 8; ++k) {
        const int base = k * IMG4 + ofs;

        // ---- phase A: issue all 9 loads (branchless, clamped) ----
        const float4 qc = x4[base];
        const float4 q0 = x4[v0 ? base - 2064 : base];
        const float4 q1 = x4[v1 ? base - 2048 : base];
        const float4 q2 = x4[v2 ? base - 2032 : base];
        const float4 q3 = x4[v3 ? base - 16   : base];
        const float4 q5 = x4[v5 ? base + 16   : base];
        const float4 q6 = x4[v6 ? base + 2032 : base];
        const float4 q7 = x4[v7 ? base + 2048 : base];
        const float4 q8 = x4[v8 ? base + 2064 : base];

        // ---- phase B: center-row byte offsets (bp*8 entries * 4 B = bp<<5) ----
        const int ip4x = qbin(qc.x, xmin, scale) << 5;
        const int ip4y = qbin(qc.y, xmin, scale) << 5;
        const int ip4z = qbin(qc.z, xmin, scale) << 5;
        const int ip4w = qbin(qc.w, xmin, scale) << 5;

        float ax = 0.f, ay = 0.f, az = 0.f, aw = 0.f;

#define ACC(Q, WZ) { \
        const int a_x = ip4x + (qbin(Q.x, xmin, scale) << 2); \
        const int a_y = ip4y + (qbin(Q.y, xmin, scale) << 2); \
        const int a_z = ip4z + (qbin(Q.z, xmin, scale) << 2); \
        const int a_w = ip4w + (qbin(Q.w, xmin, scale) << 2); \
        ax = fmaf((WZ) * Q.x, __int_as_float(__builtin_amdgcn_ds_bpermute(a_x, co_i)), ax); \
        ay = fmaf((WZ) * Q.y, __int_as_float(__builtin_amdgcn_ds_bpermute(a_y, co_i)), ay); \
        az = fmaf((WZ) * Q.z, __int_as_float(__builtin_amdgcn_ds_bpermute(a_z, co_i)), az); \
        aw = fmaf((WZ) * Q.w, __int_as_float(__builtin_amdgcn_ds_bpermute(a_w, co_i)), aw); }

        ACC(q0, wz0) ACC(q1, wz1) ACC(q2, wz2)
        ACC(q3, wz3) ACC(qc, wz4) ACC(q5, wz5)
        ACC(q6, wz6) ACC(q7, wz7) ACC(q8, wz8)
#undef ACC

        y4[base] = make_float4(ax, ay, az, aw);
    }
}

extern "C" void kernel_launch(void* const* d_in, const int* in_sizes, int n_in,
                              void* d_out, int out_size, void* d_ws, size_t ws_size,
                              hipStream_t stream) {
    const float4* x4 = (const float4*)d_in[0];
    const float*  co = (const float*)d_in[1];
    const float*  wsp = (const float*)d_in[2];
    float4* y4 = (float4*)d_out;
    float2* part = (float2*)d_ws;    // 2048 float2 = 16 KB scratch

    hipLaunchKernelGGL(reduce_k, dim3(RBLK), dim3(NTHR), 0, stream, x4, part);
    hipLaunchKernelGGL(coll_k, dim3(NBLK), dim3(NTHR), 0, stream,
                       x4, co, wsp, y4, part);
}